// Round 14
// baseline (553.053 us; speedup 1.0000x reference)
//
#include <hip/hip_runtime.h>
#include <hip/hip_bf16.h>
#include <math.h>

// LocalRelationBlock fused kernel for MI355X (gfx950).
// B=8192, C=256, H=W=5, G=8 groups, SE_HID=64.
// R14 = R13 (528us) + 3-bit XOR swizzle ((row>>3)&7)<<4 on the y1n grid's
//       column offsets (GN1 write + conv2 read). Kills the 5-way diagonal
//       bank conflict (grid diagonal = Δrow 8 = same bank group under any
//       linear stride). Keys held in named scalars, rotated per triple.

typedef short v8s  __attribute__((ext_vector_type(8)));   // 8 x bf16
typedef short v4s  __attribute__((ext_vector_type(4)));   // 4 x bf16
typedef float v16f __attribute__((ext_vector_type(16)));
typedef float v4f  __attribute__((ext_vector_type(4)));

#define NTHREADS 512
#define NB 2
#define CPB 560              // row stride bytes (140 dw)
#define YROWS 49
#define YSB (YROWS*CPB)      // 27440 bytes per sample

#define Y_BYTES  (NB*YSB)                 // 54880
#define GB_OFF   (Y_BYTES)                // g1,b1,g2,b2 : 1024 f32
#define MASK_OFF (GB_OFF + 4096)          // [NB][32] f32
#define POOL_OFF (MASK_OFF + 256)         // [NB][256] f32
#define H_OFF    (POOL_OFF + 2048)        // [NB][64] f32
#define GATE_OFF (H_OFF + 512)            // [NB][256] f32
#define INVD_OFF (GATE_OFF + 2048)        // [NB] f32
#define SMEM_BYTES (INVD_OFF + 64)        // 63904

__device__ __forceinline__ unsigned short f2bf(float f){
  return __bfloat16_as_ushort(__float2bfloat16(f));   // RTNE, hw cvt
}
// tanh-form GELU (7 VALU + 2 trans), |err| ~3e-4
__device__ __forceinline__ float gelu_f(float v){
  const float K1 = 2.3021182016f;     // 0.7978845608 * 2 * log2(e)
  const float K2 = 0.1029445404f;     // 0.7978845608*0.044715 * 2 * log2(e)
  float v2 = v*v;
  float w  = fmaf(K2, v2, K1);
  float e  = __builtin_amdgcn_exp2f(v*w);
  float r  = __builtin_amdgcn_rcpf(1.0f + e);
  float th = fmaf(-2.0f, r, 1.0f);    // tanh(u)
  float hv = 0.5f*v;
  return fmaf(hv, th, hv);
}

__device__ __forceinline__ void v16store(char* dst, const v16f &v){
  #pragma unroll
  for (int q=0;q<4;++q){
    v4f t; t[0]=v[4*q]; t[1]=v[4*q+1]; t[2]=v[4*q+2]; t[3]=v[4*q+3];
    *(v4f*)(dst + q*1024) = t;
  }
}
__device__ __forceinline__ void v16addload(const char* src, v16f &v){
  #pragma unroll
  for (int q=0;q<4;++q){
    v4f t = *(const v4f*)(src + q*1024);
    v[4*q]+=t[0]; v[4*q+1]+=t[1]; v[4*q+2]+=t[2]; v[4*q+3]+=t[3];
  }
}

// W1 -> [s=0..15][o=256][16] (k = s*16+kk).
// W2 -> kh-major LINEAR panels: [kh][tap][u][o=256][16], k = kh*128+u*16+kk.
__global__ void prep_kernel(const float* __restrict__ W1, const float* __restrict__ W2,
                            const float* __restrict__ fc1w, const float* __restrict__ fc2w,
                            unsigned short* __restrict__ w1p, unsigned short* __restrict__ w2p,
                            float* __restrict__ fc1t, float* __restrict__ fc2t)
{
  int t = blockIdx.x*blockDim.x + threadIdx.x;
  int stride = gridDim.x*blockDim.x;
  for (int i=t; i<16*256*16; i+=stride){
    int s=i>>12, o=(i>>4)&255, kk=i&15;
    w1p[i] = f2bf(W1[o*256 + s*16 + kk]);
  }
  for (int i=t; i<144*256*16; i+=stride){
    int s=i>>12, o=(i>>4)&255, kk=i&15;
    int kh = (s >= 72) ? 1 : 0;
    int r  = s - kh*72;
    int tap = r>>3, u = r&7;
    int ck = kh*128 + u*16 + kk;
    w2p[i] = f2bf(W2[o*2304 + ck*9 + tap]);
  }
  for (int i=t; i<256*64; i+=stride){ int c=i>>6, h=i&63; fc1t[i]=fc1w[h*256+c]; }
  for (int i=t; i<64*256; i+=stride){ int k=i>>8, c=i&255; fc2t[i]=fc2w[c*64+k]; }
}

__global__ __launch_bounds__(NTHREADS, 4) void lrb_main(
    const float* __restrict__ xg, const float* __restrict__ maskg,
    const float* __restrict__ g1, const float* __restrict__ b1,
    const float* __restrict__ g2, const float* __restrict__ b2,
    const unsigned short* __restrict__ w1p, const unsigned short* __restrict__ w2p,
    const float* __restrict__ fc1t, const float* __restrict__ fc1b,
    const float* __restrict__ fc2t, const float* __restrict__ fc2b,
    float* __restrict__ outg, float* __restrict__ gateg)
{
  extern __shared__ char smem[];
  float* OUTF = (float*)smem;                  // [NB][256][25] f32 reuses Y
  float* GB   = (float*)(smem + GB_OFF);
  float* MS   = (float*)(smem + MASK_OFF);
  float* POOL = (float*)(smem + POOL_OFF);
  float* HS   = (float*)(smem + H_OFF);
  float* GT   = (float*)(smem + GATE_OFF);
  float* INVD = (float*)(smem + INVD_OFF);

  const int tid  = threadIdx.x;
  const int lane = tid & 63;
  const int wid  = tid >> 6;     // 0..7
  const int mp   = wid >> 1;     // M-pair for conv2 (groups 2mp, 2mp+1)
  const int kh   = wid & 1;      // K-half for conv2; also kept sample
  const int p    = lane & 31;    // pixel slot (MFMA col / A row)
  const int half = lane >> 5;    // k-half within 16
  const int hx   = half << 4;    // byte offset of k-half within 32B k-slice
  const bool pv  = (p < 25);
  const int b0   = blockIdx.x * NB;

  // ---------------- phase 1: zero rows 25..48, stage params + mask ----------
  {
    int4 z4; z4.x=z4.y=z4.z=z4.w=0;
    for (int i = tid; i < NB*24*35; i += NTHREADS){
      int nbb = i / 840;
      int rem = i - nbb*840;
      int rr  = 25 + rem/35, cc = rem - (rem/35)*35;
      *(int4*)(smem + nbb*YSB + rr*CPB + cc*16) = z4;
    }
    if (tid < 256){
      GB[tid]=g1[tid]; GB[256+tid]=b1[tid]; GB[512+tid]=g2[tid]; GB[768+tid]=b2[tid];
    }
    if (tid >= 256 && tid < 256 + NB*32){
      int t2 = tid - 256;
      int nbb = t2>>5, pp = t2&31;
      MS[t2] = (pp < 25) ? maskg[(size_t)(b0+nbb)*25 + pp] : 0.f;
    }
  }

  // ---------------- geometry ----------------
  const int pr = p/5, ps = p - 5*(p/5);
  const int pbase = pv ? (7*pr + ps) : 0;
  const int bcol  = hx + kh*256;                 // byte column within row, conv2 B
  const char* w1c = (const char*)w1p;
  const char* w2c = (const char*)w2p;
  const int aoff1 = (wid*32 + p)*32 + hx;        // conv1 A byte off in panel
  // conv2 A: linear stream base for this wave's (kh, mp, p, half)
  const char* w2k = w2c + kh*589824 + mp*2048 + p*32 + hx;
  const char* Yb1[2] = { smem + p*CPB + hx, smem + YSB + p*CPB + hx };

  // conv1 A prologue (global; independent of LDS)
  v8s A1[3], B1[3][2];
  #pragma unroll
  for (int s0=0; s0<3; ++s0) A1[s0] = *(const v8s*)(w1c + s0*8192 + aoff1);

  // ---------------- phase 2: stage x -> Y rows 0..24 as bf16 [p][c] --------
  for (int i = tid; i < NB*25*32; i += NTHREADS){
    int nbb = i / 800;
    int rem = i - nbb*800;
    int pp  = rem >> 5;        // 0..24
    int c8  = rem & 31;        // channel octet
    const float* src = xg + ((size_t)(b0+nbb)*256 + c8*8)*25 + pp;
    v8s pk;
    #pragma unroll
    for (int k=0;k<8;++k) pk[k] = (short)f2bf(src[k*25]);
    *(v8s*)(smem + nbb*YSB + pp*CPB + c8*16) = pk;
  }
  __syncthreads();

  if (tid < NB){
    float s=0.f;
    #pragma unroll
    for (int pp=0;pp<25;++pp) s += MS[tid*32+pp];
    INVD[tid] = __builtin_amdgcn_rcpf(fmaxf(s, 1e-8f));
  }

  // ---------------- conv1 (1x1): 16 K-steps, wave = Mgroup wid -------------
  v16f acc1_0, acc1_1;
  #pragma unroll
  for (int j=0;j<16;++j){ acc1_0[j]=0.f; acc1_1[j]=0.f; }
  #pragma unroll
  for (int s0=0; s0<3; ++s0){
    B1[s0][0] = *(const v8s*)(Yb1[0] + s0*32);
    B1[s0][1] = *(const v8s*)(Yb1[1] + s0*32);
  }
  #pragma unroll
  for (int s=0; s<16; ++s){
    __builtin_amdgcn_s_setprio(1);
    acc1_0 = __builtin_amdgcn_mfma_f32_32x32x16_bf16(A1[s%3], B1[s%3][0], acc1_0, 0,0,0);
    acc1_1 = __builtin_amdgcn_mfma_f32_32x32x16_bf16(A1[s%3], B1[s%3][1], acc1_1, 0,0,0);
    __builtin_amdgcn_s_setprio(0);
    if (s+3 < 16){
      A1[s%3] = *(const v8s*)(w1c + (s+3)*8192 + aoff1);
      B1[s%3][0] = *(const v8s*)(Yb1[0] + (s+3)*32);
      B1[s%3][1] = *(const v8s*)(Yb1[1] + (s+3)*32);
    }
  }

  // ---------------- GN1 (wave's 32 ch = one group) + GELU -> grid ----------
  // Grid writes are column-XOR-swizzled with key ((row>>3)&7)<<4.
  {
    float s0a=0.f,q0a=0.f,s1a=0.f,q1a=0.f;
    #pragma unroll
    for (int j=0;j<16;++j){
      float v0 = acc1_0[j], v1 = acc1_1[j];
      s0a+=v0; q0a+=v0*v0; s1a+=v1; q1a+=v1*v1;
    }
    #pragma unroll
    for (int off=1; off<64; off<<=1){
      s0a += __shfl_xor(s0a, off, 64); q0a += __shfl_xor(q0a, off, 64);
      s1a += __shfl_xor(s1a, off, 64); q1a += __shfl_xor(q1a, off, 64);
    }
    __syncthreads();   // all conv1 LDS reads complete before grid overwrite

    const int grow = pbase + 8;
    const int kw   = ((grow>>3)&7)<<4;          // swizzle key for this row
    float mu0 = s0a*(1.f/800.f), mu1 = s1a*(1.f/800.f);
    float rstd0 = rsqrtf(q0a*(1.f/800.f) - mu0*mu0 + 1e-5f);
    float rstd1 = rsqrtf(q1a*(1.f/800.f) - mu1*mu1 + 1e-5f);
    if (pv){
      const int baseo = wid*64 + half*8;
      #pragma unroll
      for (int nt=0; nt<2; ++nt){
        float mu = nt ? mu1 : mu0, rstd = nt ? rstd1 : rstd0;
        char* dst = smem + nt*YSB + grow*CPB;
        #pragma unroll
        for (int q=0;q<4;++q){
          v4s pk;
          #pragma unroll
          for (int i2=0;i2<4;++i2){
            int ch = wid*32 + q*8 + half*4 + i2;
            float v = nt ? acc1_1[4*q+i2] : acc1_0[4*q+i2];
            float f = (v-mu)*rstd*GB[ch]+GB[256+ch];
            pk[i2] = (short)f2bf(gelu_f(f));
          }
          *(v4s*)(dst + ((baseo + q*16) ^ kw)) = pk;
        }
      }
    }
  }
  // re-zero border rows dirtied by staging (rows 0..7,13,14,20,21)
  {
    int4 z4; z4.x=z4.y=z4.z=z4.w=0;
    for (int i = tid; i < NB*12*35; i += NTHREADS){
      int nbb = i / 420;
      int rem = i - nbb*420;
      int rr  = rem/35, cc = rem - (rem/35)*35;
      int row = rr < 8 ? rr : (rr < 10 ? rr + 5 : rr + 10);
      *(int4*)(smem + nbb*YSB + row*CPB + cc*16) = z4;
    }
  }

  // conv2 A prologue (global, linear stream) before the barrier
  v8s A2[3][2], B2[3][2];
  #pragma unroll
  for (int s0=0; s0<3; ++s0){
    A2[s0][0] = *(const v8s*)(w2k + s0*8192);
    A2[s0][1] = *(const v8s*)(w2k + s0*8192 + 1024);
  }
  __syncthreads();

  // ---------------- conv2: K-split, 72 steps/wave = 3 triples of 24 --------
  v16f acc2_00, acc2_01, acc2_10, acc2_11;   // [mg2][sample]
  #pragma unroll
  for (int j=0;j<16;++j){ acc2_00[j]=0.f; acc2_01[j]=0.f; acc2_10[j]=0.f; acc2_11[j]=0.f; }

  {
    int bq = pv ? pbase*CPB : 41*CPB;
    const int bd = pv ? 7*CPB : 0;
    int rq = pv ? pbase : 41;                 // base grid row of current triple
    const int rd = pv ? 7 : 0;
    int tb = 0;
    // swizzle keys: this triple's taps (rows rq,rq+1,rq+2) + next triple tap0
    int k0  = ((rq>>3)&7)<<4;
    int k1  = (((rq+1)>>3)&7)<<4;
    int k2  = (((rq+2)>>3)&7)<<4;
    int kn0 = (((rq+rd)>>3)&7)<<4;

    #pragma unroll
    for (int s0=0; s0<3; ++s0){
      int cx = (bcol + s0*32) ^ k0;
      B2[s0][0] = *(const v8s*)(smem + bq + cx);
      B2[s0][1] = *(const v8s*)(smem + YSB + bq + cx);
    }

#define C2_STEP(S, PF) do { \
    __builtin_amdgcn_s_setprio(1); \
    acc2_00 = __builtin_amdgcn_mfma_f32_32x32x16_bf16(A2[(S)%3][0], B2[(S)%3][0], acc2_00, 0,0,0); \
    acc2_01 = __builtin_amdgcn_mfma_f32_32x32x16_bf16(A2[(S)%3][0], B2[(S)%3][1], acc2_01, 0,0,0); \
    acc2_10 = __builtin_amdgcn_mfma_f32_32x32x16_bf16(A2[(S)%3][1], B2[(S)%3][0], acc2_10, 0,0,0); \
    acc2_11 = __builtin_amdgcn_mfma_f32_32x32x16_bf16(A2[(S)%3][1], B2[(S)%3][1], acc2_11, 0,0,0); \
    __builtin_amdgcn_s_setprio(0); \
    if (PF) { \
      const char* ap_ = w2k + tb + ((S)+3)*8192; \
      A2[(S)%3][0] = *(const v8s*)(ap_); \
      A2[(S)%3][1] = *(const v8s*)(ap_ + 1024); \
      const int s3_ = (S)+3; \
      const int kk_ = (s3_ < 24) ? ((s3_>>3)==0 ? k0 : ((s3_>>3)==1 ? k1 : k2)) : kn0; \
      const int ro_ = (s3_ < 24) ? (s3_>>3)*CPB : 7*CPB; \
      const int cx_ = (bcol + (s3_&7)*32) ^ kk_; \
      B2[(S)%3][0] = *(const v8s*)(smem + bq + ro_ + cx_); \
      B2[(S)%3][1] = *(const v8s*)(smem + YSB + bq + ro_ + cx_); \
    } \
  } while(0)

    #pragma unroll 1
    for (int tr=0; tr<2; ++tr){
      #pragma unroll
      for (int s=0; s<24; ++s) C2_STEP(s, 1);
      tb += 196608;          // 24 panels * 8192
      bq += bd;              // +7 rows per triple
      rq += rd;
      k0  = kn0;
      k1  = (((rq+1)>>3)&7)<<4;
      k2  = (((rq+2)>>3)&7)<<4;
      kn0 = (((rq+rd)>>3)&7)<<4;
    }
    #pragma unroll
    for (int s=0; s<21; ++s) C2_STEP(s, 1);
    #pragma unroll
    for (int s=21; s<24; ++s) C2_STEP(s, 0);
#undef C2_STEP
  }
  __syncthreads();   // conv2 LDS reads done; Y becomes exchange window

  // ---------------- cross-wave K-reduction via LDS overlay (2 rounds) ------
  {
    char* EXw = smem + (kh^1)*16384 + mp*4096 + (lane<<4);
    const char* EXr = smem + kh*16384 + mp*4096 + (lane<<4);
    if (kh==0) v16store(EXw, acc2_01); else v16store(EXw, acc2_00);
    __syncthreads();
    if (kh==0) v16addload(EXr, acc2_00); else v16addload(EXr, acc2_01);
    __syncthreads();
    if (kh==0) v16store(EXw, acc2_11); else v16store(EXw, acc2_10);
    __syncthreads();
    if (kh==0) v16addload(EXr, acc2_10); else v16addload(EXr, acc2_11);
  }
  // kept sample = kh; F0 = group 2mp, F1 = group 2mp+1
  v16f F0 = (kh==0) ? acc2_00 : acc2_01;
  v16f F1 = (kh==0) ? acc2_10 : acc2_11;

  // ---------------- GN2 + GELU + residual -> OUTF ----------
  {
    float s0a=0.f,q0a=0.f,s1a=0.f,q1a=0.f;
    #pragma unroll
    for (int j=0;j<16;++j){
      float v0=F0[j], v1=F1[j];
      s0a+=v0; q0a+=v0*v0; s1a+=v1; q1a+=v1*v1;
    }
    #pragma unroll
    for (int off=1; off<64; off<<=1){
      s0a += __shfl_xor(s0a, off, 64); q0a += __shfl_xor(q0a, off, 64);
      s1a += __shfl_xor(s1a, off, 64); q1a += __shfl_xor(q1a, off, 64);
    }
    __syncthreads();   // exchange reads complete; OUTF region free

    float mu0 = s0a*(1.f/800.f), mu1 = s1a*(1.f/800.f);
    float rstd0 = rsqrtf(q0a*(1.f/800.f) - mu0*mu0 + 1e-5f);
    float rstd1 = rsqrtf(q1a*(1.f/800.f) - mu1*mu1 + 1e-5f);
    const float* xr = xg + ((size_t)(b0+kh)*256 + mp*64)*25 + p;
    if (pv){
      #pragma unroll
      for (int j=0;j<16;++j){
        int crow = (j&3) + 8*(j>>2) + 4*half;
        {
          int ch = mp*64 + crow;
          float f = (F0[j]-mu0)*rstd0*GB[512+ch]+GB[768+ch];
          f = gelu_f(f) + xr[crow*25];
          OUTF[kh*6400 + ch*25 + p] = f;
        }
        {
          int ch = mp*64 + 32 + crow;
          float f = (F1[j]-mu1)*rstd1*GB[512+ch]+GB[768+ch];
          f = gelu_f(f) + xr[(32+crow)*25];
          OUTF[kh*6400 + ch*25 + p] = f;
        }
      }
    }
  }
  __syncthreads();

  // ---------------- masked pooling via OUTF re-read (conflict-free) --------
  {
    int nbb = tid >> 8, ch = tid & 255;
    const float* of = OUTF + nbb*6400 + ch*25;
    const float* ms = MS + nbb*32;
    float dot = 0.f;
    #pragma unroll
    for (int pp=0; pp<25; ++pp) dot = fmaf(of[pp], ms[pp], dot);
    POOL[nbb*256 + ch] = dot;
  }
  __syncthreads();

  // ---------------- SE FC1: 4-way split dot + shuffle combine --------------
  {
    int nbb  = tid >> 8;          // 0..1
    int hid  = (tid >> 2) & 63;
    int part = tid & 3;
    const float* pl = POOL + nbb*256 + part*64;
    const float* wp = fc1t + part*64*64 + hid;
    float dot = 0.f;
    #pragma unroll 8
    for (int c=0;c<64;++c) dot += wp[c*64]*pl[c];
    dot += __shfl_xor(dot, 1, 64);
    dot += __shfl_xor(dot, 2, 64);
    if (part == 0)
      HS[nbb*64+hid] = gelu_f(fmaf(INVD[nbb], dot, fc1b[hid]));
  }
  __syncthreads();
  // ---------------- SE FC2 -> sigmoid gate (LDS + global) -----------------
  {
    int ch = tid & 255, nbb = tid >> 8;
    const float* hp = HS + nbb*64;
    float dot = 0.f;
    #pragma unroll 8
    for (int k=0;k<64;++k) dot += fc2t[k*256+ch]*hp[k];
    dot += fc2b[ch];
    float gv = __builtin_amdgcn_rcpf(1.0f + __builtin_amdgcn_exp2f(-dot*1.4426950408889634f));
    GT[nbb*256+ch] = gv;
    gateg[(size_t)(b0+nbb)*256+ch] = gv;
  }
  __syncthreads();

  // ---------------- final coalesced store: out = OUTF * gate * mask -------
  for (int i = tid; i < NB*1600; i += NTHREADS){
    int nbb = i / 1600;
    int r4  = i - nbb*1600;
    int e0  = r4*4;
    v4f o4 = *(const v4f*)(OUTF + nbb*6400 + e0);
    #pragma unroll
    for (int k=0;k<4;++k){
      int e = e0+k;
      int ch = e/25;
      int pp = e - ch*25;
      o4[k] = o4[k] * GT[nbb*256+ch] * MS[nbb*32+pp];
    }
    *(v4f*)(outg + (size_t)(b0+nbb)*6400 + e0) = o4;
  }
}

extern "C" void kernel_launch(void* const* d_in, const int* in_sizes, int n_in,
                              void* d_out, int out_size, void* d_ws, size_t ws_size,
                              hipStream_t stream)
{
  const float* xg   = (const float*)d_in[0];
  const float* pm   = (const float*)d_in[1];
  const float* W1   = (const float*)d_in[2];
  const float* g1   = (const float*)d_in[3];
  const float* b1   = (const float*)d_in[4];
  const float* W2   = (const float*)d_in[5];
  const float* g2   = (const float*)d_in[6];
  const float* b2   = (const float*)d_in[7];
  const float* fc1w = (const float*)d_in[8];
  const float* fc1b = (const float*)d_in[9];
  const float* fc2w = (const float*)d_in[10];
  const float* fc2b = (const float*)d_in[11];

  float* outg  = (float*)d_out;
  float* gateg = outg + (size_t)8192*256*25;

  unsigned short* w1p = (unsigned short*)d_ws;        // 16*256*16 bf16
  unsigned short* w2p = w1p + 16*256*16;              // 144*256*16 bf16 (kh-major linear)
  float* fc1t = (float*)(w2p + 144*256*16);           // 256*64 f32 (transposed)
  float* fc2t = fc1t + 256*64;                        // 64*256 f32 (transposed)

  prep_kernel<<<dim3(512), dim3(256), 0, stream>>>(W1, W2, fc1w, fc2w, w1p, w2p, fc1t, fc2t);

  hipFuncSetAttribute(reinterpret_cast<const void*>(lrb_main),
                      hipFuncAttributeMaxDynamicSharedMemorySize, (int)SMEM_BYTES);
  lrb_main<<<dim3(4096), dim3(NTHREADS), SMEM_BYTES, stream>>>(
      xg, pm, g1, b1, g2, b2, w1p, w2p, fc1t, fc1b, fc2t, fc2b, outg, gateg);
}

// Round 15
// 539.698 us; speedup vs baseline: 1.0247x; 1.0247x over previous
//
#include <hip/hip_runtime.h>
#include <hip/hip_bf16.h>
#include <math.h>

// LocalRelationBlock fused kernel for MI355X (gfx950).
// B=8192, C=256, H=W=5, G=8 groups, SE_HID=64.
// R15 = R13 (best, 528.1us) with s_setprio removed (single-variable A/B:
//       T5/m190 says setprio is ~0..-1.5% on lockstep structures; it was
//       bundled into R6 and never isolated; costs 288 SALU in the hot loop).
//       Everything else byte-identical to R13.

typedef short v8s  __attribute__((ext_vector_type(8)));   // 8 x bf16
typedef short v4s  __attribute__((ext_vector_type(4)));   // 4 x bf16
typedef float v16f __attribute__((ext_vector_type(16)));
typedef float v4f  __attribute__((ext_vector_type(4)));

#define NTHREADS 512
#define NB 2
#define CPB 560              // row stride bytes (140 dw)
#define YROWS 49
#define YSB (YROWS*CPB)      // 27440 bytes per sample

#define Y_BYTES  (NB*YSB)                 // 54880
#define GB_OFF   (Y_BYTES)                // g1,b1,g2,b2 : 1024 f32
#define MASK_OFF (GB_OFF + 4096)          // [NB][32] f32
#define POOL_OFF (MASK_OFF + 256)         // [NB][256] f32
#define H_OFF    (POOL_OFF + 2048)        // [NB][64] f32
#define GATE_OFF (H_OFF + 512)            // [NB][256] f32
#define INVD_OFF (GATE_OFF + 2048)        // [NB] f32
#define SMEM_BYTES (INVD_OFF + 64)        // 63904

__device__ __forceinline__ unsigned short f2bf(float f){
  return __bfloat16_as_ushort(__float2bfloat16(f));   // RTNE, hw cvt
}
// tanh-form GELU (7 VALU + 2 trans), |err| ~3e-4
__device__ __forceinline__ float gelu_f(float v){
  const float K1 = 2.3021182016f;     // 0.7978845608 * 2 * log2(e)
  const float K2 = 0.1029445404f;     // 0.7978845608*0.044715 * 2 * log2(e)
  float v2 = v*v;
  float w  = fmaf(K2, v2, K1);
  float e  = __builtin_amdgcn_exp2f(v*w);
  float r  = __builtin_amdgcn_rcpf(1.0f + e);
  float th = fmaf(-2.0f, r, 1.0f);    // tanh(u)
  float hv = 0.5f*v;
  return fmaf(hv, th, hv);
}

__device__ __forceinline__ void v16store(char* dst, const v16f &v){
  #pragma unroll
  for (int q=0;q<4;++q){
    v4f t; t[0]=v[4*q]; t[1]=v[4*q+1]; t[2]=v[4*q+2]; t[3]=v[4*q+3];
    *(v4f*)(dst + q*1024) = t;
  }
}
__device__ __forceinline__ void v16addload(const char* src, v16f &v){
  #pragma unroll
  for (int q=0;q<4;++q){
    v4f t = *(const v4f*)(src + q*1024);
    v[4*q]+=t[0]; v[4*q+1]+=t[1]; v[4*q+2]+=t[2]; v[4*q+3]+=t[3];
  }
}

// W1 -> [s=0..15][o=256][16] (k = s*16+kk).
// W2 -> kh-major LINEAR panels: [kh][tap][u][o=256][16], k = kh*128+u*16+kk.
__global__ void prep_kernel(const float* __restrict__ W1, const float* __restrict__ W2,
                            const float* __restrict__ fc1w, const float* __restrict__ fc2w,
                            unsigned short* __restrict__ w1p, unsigned short* __restrict__ w2p,
                            float* __restrict__ fc1t, float* __restrict__ fc2t)
{
  int t = blockIdx.x*blockDim.x + threadIdx.x;
  int stride = gridDim.x*blockDim.x;
  for (int i=t; i<16*256*16; i+=stride){
    int s=i>>12, o=(i>>4)&255, kk=i&15;
    w1p[i] = f2bf(W1[o*256 + s*16 + kk]);
  }
  for (int i=t; i<144*256*16; i+=stride){
    int s=i>>12, o=(i>>4)&255, kk=i&15;
    int kh = (s >= 72) ? 1 : 0;
    int r  = s - kh*72;
    int tap = r>>3, u = r&7;
    int ck = kh*128 + u*16 + kk;
    w2p[i] = f2bf(W2[o*2304 + ck*9 + tap]);
  }
  for (int i=t; i<256*64; i+=stride){ int c=i>>6, h=i&63; fc1t[i]=fc1w[h*256+c]; }
  for (int i=t; i<64*256; i+=stride){ int k=i>>8, c=i&255; fc2t[i]=fc2w[c*64+k]; }
}

__global__ __launch_bounds__(NTHREADS, 4) void lrb_main(
    const float* __restrict__ xg, const float* __restrict__ maskg,
    const float* __restrict__ g1, const float* __restrict__ b1,
    const float* __restrict__ g2, const float* __restrict__ b2,
    const unsigned short* __restrict__ w1p, const unsigned short* __restrict__ w2p,
    const float* __restrict__ fc1t, const float* __restrict__ fc1b,
    const float* __restrict__ fc2t, const float* __restrict__ fc2b,
    float* __restrict__ outg, float* __restrict__ gateg)
{
  extern __shared__ char smem[];
  float* OUTF = (float*)smem;                  // [NB][256][25] f32 reuses Y
  float* GB   = (float*)(smem + GB_OFF);
  float* MS   = (float*)(smem + MASK_OFF);
  float* POOL = (float*)(smem + POOL_OFF);
  float* HS   = (float*)(smem + H_OFF);
  float* GT   = (float*)(smem + GATE_OFF);
  float* INVD = (float*)(smem + INVD_OFF);

  const int tid  = threadIdx.x;
  const int lane = tid & 63;
  const int wid  = tid >> 6;     // 0..7
  const int mp   = wid >> 1;     // M-pair for conv2 (groups 2mp, 2mp+1)
  const int kh   = wid & 1;      // K-half for conv2; also kept sample
  const int p    = lane & 31;    // pixel slot (MFMA col / A row)
  const int half = lane >> 5;    // k-half within 16
  const int hx   = half << 4;    // byte offset of k-half within 32B k-slice
  const bool pv  = (p < 25);
  const int b0   = blockIdx.x * NB;

  // ---------------- phase 1: zero rows 25..48, stage params + mask ----------
  {
    int4 z4; z4.x=z4.y=z4.z=z4.w=0;
    for (int i = tid; i < NB*24*35; i += NTHREADS){
      int nbb = i / 840;
      int rem = i - nbb*840;
      int rr  = 25 + rem/35, cc = rem - (rem/35)*35;
      *(int4*)(smem + nbb*YSB + rr*CPB + cc*16) = z4;
    }
    if (tid < 256){
      GB[tid]=g1[tid]; GB[256+tid]=b1[tid]; GB[512+tid]=g2[tid]; GB[768+tid]=b2[tid];
    }
    if (tid >= 256 && tid < 256 + NB*32){
      int t2 = tid - 256;
      int nbb = t2>>5, pp = t2&31;
      MS[t2] = (pp < 25) ? maskg[(size_t)(b0+nbb)*25 + pp] : 0.f;
    }
  }

  // ---------------- geometry ----------------
  const int pr = p/5, ps = p - 5*(p/5);
  const int pbase = pv ? (7*pr + ps) : 0;
  const int bcol  = hx + kh*256;                 // byte column within row, conv2 B
  const char* w1c = (const char*)w1p;
  const char* w2c = (const char*)w2p;
  const int aoff1 = (wid*32 + p)*32 + hx;        // conv1 A byte off in panel
  // conv2 A: linear stream base for this wave's (kh, mp, p, half)
  const char* w2k = w2c + kh*589824 + mp*2048 + p*32 + hx;
  const char* Yb1[2] = { smem + p*CPB + hx, smem + YSB + p*CPB + hx };

  // conv1 A prologue (global; independent of LDS)
  v8s A1[3], B1[3][2];
  #pragma unroll
  for (int s0=0; s0<3; ++s0) A1[s0] = *(const v8s*)(w1c + s0*8192 + aoff1);

  // ---------------- phase 2: stage x -> Y rows 0..24 as bf16 [p][c] --------
  for (int i = tid; i < NB*25*32; i += NTHREADS){
    int nbb = i / 800;
    int rem = i - nbb*800;
    int pp  = rem >> 5;        // 0..24
    int c8  = rem & 31;        // channel octet
    const float* src = xg + ((size_t)(b0+nbb)*256 + c8*8)*25 + pp;
    v8s pk;
    #pragma unroll
    for (int k=0;k<8;++k) pk[k] = (short)f2bf(src[k*25]);
    *(v8s*)(smem + nbb*YSB + pp*CPB + c8*16) = pk;
  }
  __syncthreads();

  if (tid < NB){
    float s=0.f;
    #pragma unroll
    for (int pp=0;pp<25;++pp) s += MS[tid*32+pp];
    INVD[tid] = __builtin_amdgcn_rcpf(fmaxf(s, 1e-8f));
  }

  // ---------------- conv1 (1x1): 16 K-steps, wave = Mgroup wid -------------
  v16f acc1_0, acc1_1;
  #pragma unroll
  for (int j=0;j<16;++j){ acc1_0[j]=0.f; acc1_1[j]=0.f; }
  #pragma unroll
  for (int s0=0; s0<3; ++s0){
    B1[s0][0] = *(const v8s*)(Yb1[0] + s0*32);
    B1[s0][1] = *(const v8s*)(Yb1[1] + s0*32);
  }
  #pragma unroll
  for (int s=0; s<16; ++s){
    acc1_0 = __builtin_amdgcn_mfma_f32_32x32x16_bf16(A1[s%3], B1[s%3][0], acc1_0, 0,0,0);
    acc1_1 = __builtin_amdgcn_mfma_f32_32x32x16_bf16(A1[s%3], B1[s%3][1], acc1_1, 0,0,0);
    if (s+3 < 16){
      A1[s%3] = *(const v8s*)(w1c + (s+3)*8192 + aoff1);
      B1[s%3][0] = *(const v8s*)(Yb1[0] + (s+3)*32);
      B1[s%3][1] = *(const v8s*)(Yb1[1] + (s+3)*32);
    }
  }

  // ---------------- GN1 (wave's 32 ch = one group) + GELU -> grid ----------
  {
    float s0a=0.f,q0a=0.f,s1a=0.f,q1a=0.f;
    #pragma unroll
    for (int j=0;j<16;++j){
      float v0 = acc1_0[j], v1 = acc1_1[j];
      s0a+=v0; q0a+=v0*v0; s1a+=v1; q1a+=v1*v1;
    }
    #pragma unroll
    for (int off=1; off<64; off<<=1){
      s0a += __shfl_xor(s0a, off, 64); q0a += __shfl_xor(q0a, off, 64);
      s1a += __shfl_xor(s1a, off, 64); q1a += __shfl_xor(q1a, off, 64);
    }
    __syncthreads();   // all conv1 LDS reads complete before grid overwrite

    const int grow = pbase + 8;
    float mu0 = s0a*(1.f/800.f), mu1 = s1a*(1.f/800.f);
    float rstd0 = rsqrtf(q0a*(1.f/800.f) - mu0*mu0 + 1e-5f);
    float rstd1 = rsqrtf(q1a*(1.f/800.f) - mu1*mu1 + 1e-5f);
    if (pv){
      #pragma unroll
      for (int nt=0; nt<2; ++nt){
        float mu = nt ? mu1 : mu0, rstd = nt ? rstd1 : rstd0;
        char* dst = smem + nt*YSB + grow*CPB + wid*64 + half*8;
        #pragma unroll
        for (int q=0;q<4;++q){
          v4s pk;
          #pragma unroll
          for (int i2=0;i2<4;++i2){
            int ch = wid*32 + q*8 + half*4 + i2;
            float v = nt ? acc1_1[4*q+i2] : acc1_0[4*q+i2];
            float f = (v-mu)*rstd*GB[ch]+GB[256+ch];
            pk[i2] = (short)f2bf(gelu_f(f));
          }
          *(v4s*)(dst + q*16) = pk;
        }
      }
    }
  }
  // re-zero border rows dirtied by staging (rows 0..7,13,14,20,21)
  {
    int4 z4; z4.x=z4.y=z4.z=z4.w=0;
    for (int i = tid; i < NB*12*35; i += NTHREADS){
      int nbb = i / 420;
      int rem = i - nbb*420;
      int rr  = rem/35, cc = rem - (rem/35)*35;
      int row = rr < 8 ? rr : (rr < 10 ? rr + 5 : rr + 10);
      *(int4*)(smem + nbb*YSB + row*CPB + cc*16) = z4;
    }
  }

  // conv2 A prologue (global, linear stream) before the barrier
  v8s A2[3][2], B2[3][2];
  #pragma unroll
  for (int s0=0; s0<3; ++s0){
    A2[s0][0] = *(const v8s*)(w2k + s0*8192);
    A2[s0][1] = *(const v8s*)(w2k + s0*8192 + 1024);
  }
  __syncthreads();

  // ---------------- conv2: K-split, 72 steps/wave = 3 triples of 24 --------
  v16f acc2_00, acc2_01, acc2_10, acc2_11;   // [mg2][sample]
  #pragma unroll
  for (int j=0;j<16;++j){ acc2_00[j]=0.f; acc2_01[j]=0.f; acc2_10[j]=0.f; acc2_11[j]=0.f; }

  {
    int bq = pv ? pbase*CPB : 41*CPB;
    const int bd = pv ? 7*CPB : 0;
    int tb = 0;

    #pragma unroll
    for (int s0=0; s0<3; ++s0){
      B2[s0][0] = *(const v8s*)(smem + bq + bcol + s0*32);
      B2[s0][1] = *(const v8s*)(smem + YSB + bq + bcol + s0*32);
    }

#define C2_STEP(S, PF) do { \
    acc2_00 = __builtin_amdgcn_mfma_f32_32x32x16_bf16(A2[(S)%3][0], B2[(S)%3][0], acc2_00, 0,0,0); \
    acc2_01 = __builtin_amdgcn_mfma_f32_32x32x16_bf16(A2[(S)%3][0], B2[(S)%3][1], acc2_01, 0,0,0); \
    acc2_10 = __builtin_amdgcn_mfma_f32_32x32x16_bf16(A2[(S)%3][1], B2[(S)%3][0], acc2_10, 0,0,0); \
    acc2_11 = __builtin_amdgcn_mfma_f32_32x32x16_bf16(A2[(S)%3][1], B2[(S)%3][1], acc2_11, 0,0,0); \
    if (PF) { \
      const char* ap_ = w2k + tb + ((S)+3)*8192; \
      A2[(S)%3][0] = *(const v8s*)(ap_); \
      A2[(S)%3][1] = *(const v8s*)(ap_ + 1024); \
      const int ro_ = (((S)+3) < 24) ? (((S)+3)>>3)*CPB : 7*CPB; \
      const int co_ = (((S)+3)&7)*32; \
      B2[(S)%3][0] = *(const v8s*)(smem + bq + ro_ + bcol + co_); \
      B2[(S)%3][1] = *(const v8s*)(smem + YSB + bq + ro_ + bcol + co_); \
    } \
  } while(0)

    #pragma unroll 1
    for (int tr=0; tr<2; ++tr){
      #pragma unroll
      for (int s=0; s<24; ++s) C2_STEP(s, 1);
      tb += 196608;          // 24 panels * 8192
      bq += bd;              // +7 rows (OFF7 triple stride), 0 for invalid
    }
    #pragma unroll
    for (int s=0; s<21; ++s) C2_STEP(s, 1);
    #pragma unroll
    for (int s=21; s<24; ++s) C2_STEP(s, 0);
#undef C2_STEP
  }
  __syncthreads();   // conv2 LDS reads done; Y becomes exchange window

  // ---------------- cross-wave K-reduction via LDS overlay (2 rounds) ------
  {
    char* EXw = smem + (kh^1)*16384 + mp*4096 + (lane<<4);
    const char* EXr = smem + kh*16384 + mp*4096 + (lane<<4);
    if (kh==0) v16store(EXw, acc2_01); else v16store(EXw, acc2_00);
    __syncthreads();
    if (kh==0) v16addload(EXr, acc2_00); else v16addload(EXr, acc2_01);
    __syncthreads();
    if (kh==0) v16store(EXw, acc2_11); else v16store(EXw, acc2_10);
    __syncthreads();
    if (kh==0) v16addload(EXr, acc2_10); else v16addload(EXr, acc2_11);
  }
  // kept sample = kh; F0 = group 2mp, F1 = group 2mp+1
  v16f F0 = (kh==0) ? acc2_00 : acc2_01;
  v16f F1 = (kh==0) ? acc2_10 : acc2_11;

  // ---------------- GN2 + GELU + residual -> OUTF ----------
  {
    float s0a=0.f,q0a=0.f,s1a=0.f,q1a=0.f;
    #pragma unroll
    for (int j=0;j<16;++j){
      float v0=F0[j], v1=F1[j];
      s0a+=v0; q0a+=v0*v0; s1a+=v1; q1a+=v1*v1;
    }
    #pragma unroll
    for (int off=1; off<64; off<<=1){
      s0a += __shfl_xor(s0a, off, 64); q0a += __shfl_xor(q0a, off, 64);
      s1a += __shfl_xor(s1a, off, 64); q1a += __shfl_xor(q1a, off, 64);
    }
    __syncthreads();   // exchange reads complete; OUTF region free

    float mu0 = s0a*(1.f/800.f), mu1 = s1a*(1.f/800.f);
    float rstd0 = rsqrtf(q0a*(1.f/800.f) - mu0*mu0 + 1e-5f);
    float rstd1 = rsqrtf(q1a*(1.f/800.f) - mu1*mu1 + 1e-5f);
    const float* xr = xg + ((size_t)(b0+kh)*256 + mp*64)*25 + p;
    if (pv){
      #pragma unroll
      for (int j=0;j<16;++j){
        int crow = (j&3) + 8*(j>>2) + 4*half;
        {
          int ch = mp*64 + crow;
          float f = (F0[j]-mu0)*rstd0*GB[512+ch]+GB[768+ch];
          f = gelu_f(f) + xr[crow*25];
          OUTF[kh*6400 + ch*25 + p] = f;
        }
        {
          int ch = mp*64 + 32 + crow;
          float f = (F1[j]-mu1)*rstd1*GB[512+ch]+GB[768+ch];
          f = gelu_f(f) + xr[(32+crow)*25];
          OUTF[kh*6400 + ch*25 + p] = f;
        }
      }
    }
  }
  __syncthreads();

  // ---------------- masked pooling via OUTF re-read (conflict-free) --------
  {
    int nbb = tid >> 8, ch = tid & 255;
    const float* of = OUTF + nbb*6400 + ch*25;
    const float* ms = MS + nbb*32;
    float dot = 0.f;
    #pragma unroll
    for (int pp=0; pp<25; ++pp) dot = fmaf(of[pp], ms[pp], dot);
    POOL[nbb*256 + ch] = dot;
  }
  __syncthreads();

  // ---------------- SE FC1: 4-way split dot + shuffle combine --------------
  {
    int nbb  = tid >> 8;          // 0..1
    int hid  = (tid >> 2) & 63;
    int part = tid & 3;
    const float* pl = POOL + nbb*256 + part*64;
    const float* wp = fc1t + part*64*64 + hid;
    float dot = 0.f;
    #pragma unroll 8
    for (int c=0;c<64;++c) dot += wp[c*64]*pl[c];
    dot += __shfl_xor(dot, 1, 64);
    dot += __shfl_xor(dot, 2, 64);
    if (part == 0)
      HS[nbb*64+hid] = gelu_f(fmaf(INVD[nbb], dot, fc1b[hid]));
  }
  __syncthreads();
  // ---------------- SE FC2 -> sigmoid gate (LDS + global) -----------------
  {
    int ch = tid & 255, nbb = tid >> 8;
    const float* hp = HS + nbb*64;
    float dot = 0.f;
    #pragma unroll 8
    for (int k=0;k<64;++k) dot += fc2t[k*256+ch]*hp[k];
    dot += fc2b[ch];
    float gv = __builtin_amdgcn_rcpf(1.0f + __builtin_amdgcn_exp2f(-dot*1.4426950408889634f));
    GT[nbb*256+ch] = gv;
    gateg[(size_t)(b0+nbb)*256+ch] = gv;
  }
  __syncthreads();

  // ---------------- final coalesced store: out = OUTF * gate * mask -------
  for (int i = tid; i < NB*1600; i += NTHREADS){
    int nbb = i / 1600;
    int r4  = i - nbb*1600;
    int e0  = r4*4;
    v4f o4 = *(const v4f*)(OUTF + nbb*6400 + e0);
    #pragma unroll
    for (int k=0;k<4;++k){
      int e = e0+k;
      int ch = e/25;
      int pp = e - ch*25;
      o4[k] = o4[k] * GT[nbb*256+ch] * MS[nbb*32+pp];
    }
    *(v4f*)(outg + (size_t)(b0+nbb)*6400 + e0) = o4;
  }
}

extern "C" void kernel_launch(void* const* d_in, const int* in_sizes, int n_in,
                              void* d_out, int out_size, void* d_ws, size_t ws_size,
                              hipStream_t stream)
{
  const float* xg   = (const float*)d_in[0];
  const float* pm   = (const float*)d_in[1];
  const float* W1   = (const float*)d_in[2];
  const float* g1   = (const float*)d_in[3];
  const float* b1   = (const float*)d_in[4];
  const float* W2   = (const float*)d_in[5];
  const float* g2   = (const float*)d_in[6];
  const float* b2   = (const float*)d_in[7];
  const float* fc1w = (const float*)d_in[8];
  const float* fc1b = (const float*)d_in[9];
  const float* fc2w = (const float*)d_in[10];
  const float* fc2b = (const float*)d_in[11];

  float* outg  = (float*)d_out;
  float* gateg = outg + (size_t)8192*256*25;

  unsigned short* w1p = (unsigned short*)d_ws;        // 16*256*16 bf16
  unsigned short* w2p = w1p + 16*256*16;              // 144*256*16 bf16 (kh-major linear)
  float* fc1t = (float*)(w2p + 144*256*16);           // 256*64 f32 (transposed)
  float* fc2t = fc1t + 256*64;                        // 64*256 f32 (transposed)

  prep_kernel<<<dim3(512), dim3(256), 0, stream>>>(W1, W2, fc1w, fc2w, w1p, w2p, fc1t, fc2t);

  hipFuncSetAttribute(reinterpret_cast<const void*>(lrb_main),
                      hipFuncAttributeMaxDynamicSharedMemorySize, (int)SMEM_BYTES);
  lrb_main<<<dim3(4096), dim3(NTHREADS), SMEM_BYTES, stream>>>(
      xg, pm, g1, b1, g2, b2, w1p, w2p, fc1t, fc1b, fc2t, fc2b, outg, gateg);
}

// Round 16
// 522.807 us; speedup vs baseline: 1.0579x; 1.0323x over previous
//
#include <hip/hip_runtime.h>
#include <hip/hip_bf16.h>
#include <math.h>

// LocalRelationBlock fused kernel for MI355X (gfx950).
// B=8192, C=256, H=W=5, G=8 groups, SE_HID=64.
// R16 = R13 restored (best measured: 528.1us). R15's A/B showed s_setprio
//       helps +2.2% on this structure (2 WG/CU phase diversity) — kept.
//       Structure: R6 conv2 K-split (wave = M-pair x K-half), 560B rows,
//       rolled triples w/ linear A-stream, f32 LDS exchange, LDS pool
//       re-read, hw bf16 cvts, tanh-GELU.

typedef short v8s  __attribute__((ext_vector_type(8)));   // 8 x bf16
typedef short v4s  __attribute__((ext_vector_type(4)));   // 4 x bf16
typedef float v16f __attribute__((ext_vector_type(16)));
typedef float v4f  __attribute__((ext_vector_type(4)));

#define NTHREADS 512
#define NB 2
#define CPB 560              // row stride bytes (140 dw)
#define YROWS 49
#define YSB (YROWS*CPB)      // 27440 bytes per sample

#define Y_BYTES  (NB*YSB)                 // 54880
#define GB_OFF   (Y_BYTES)                // g1,b1,g2,b2 : 1024 f32
#define MASK_OFF (GB_OFF + 4096)          // [NB][32] f32
#define POOL_OFF (MASK_OFF + 256)         // [NB][256] f32
#define H_OFF    (POOL_OFF + 2048)        // [NB][64] f32
#define GATE_OFF (H_OFF + 512)            // [NB][256] f32
#define INVD_OFF (GATE_OFF + 2048)        // [NB] f32
#define SMEM_BYTES (INVD_OFF + 64)        // 63904

__device__ __forceinline__ unsigned short f2bf(float f){
  return __bfloat16_as_ushort(__float2bfloat16(f));   // RTNE, hw cvt
}
// tanh-form GELU (7 VALU + 2 trans), |err| ~3e-4
__device__ __forceinline__ float gelu_f(float v){
  const float K1 = 2.3021182016f;     // 0.7978845608 * 2 * log2(e)
  const float K2 = 0.1029445404f;     // 0.7978845608*0.044715 * 2 * log2(e)
  float v2 = v*v;
  float w  = fmaf(K2, v2, K1);
  float e  = __builtin_amdgcn_exp2f(v*w);
  float r  = __builtin_amdgcn_rcpf(1.0f + e);
  float th = fmaf(-2.0f, r, 1.0f);    // tanh(u)
  float hv = 0.5f*v;
  return fmaf(hv, th, hv);
}

__device__ __forceinline__ void v16store(char* dst, const v16f &v){
  #pragma unroll
  for (int q=0;q<4;++q){
    v4f t; t[0]=v[4*q]; t[1]=v[4*q+1]; t[2]=v[4*q+2]; t[3]=v[4*q+3];
    *(v4f*)(dst + q*1024) = t;
  }
}
__device__ __forceinline__ void v16addload(const char* src, v16f &v){
  #pragma unroll
  for (int q=0;q<4;++q){
    v4f t = *(const v4f*)(src + q*1024);
    v[4*q]+=t[0]; v[4*q+1]+=t[1]; v[4*q+2]+=t[2]; v[4*q+3]+=t[3];
  }
}

// W1 -> [s=0..15][o=256][16] (k = s*16+kk).
// W2 -> kh-major LINEAR panels: [kh][tap][u][o=256][16], k = kh*128+u*16+kk.
__global__ void prep_kernel(const float* __restrict__ W1, const float* __restrict__ W2,
                            const float* __restrict__ fc1w, const float* __restrict__ fc2w,
                            unsigned short* __restrict__ w1p, unsigned short* __restrict__ w2p,
                            float* __restrict__ fc1t, float* __restrict__ fc2t)
{
  int t = blockIdx.x*blockDim.x + threadIdx.x;
  int stride = gridDim.x*blockDim.x;
  for (int i=t; i<16*256*16; i+=stride){
    int s=i>>12, o=(i>>4)&255, kk=i&15;
    w1p[i] = f2bf(W1[o*256 + s*16 + kk]);
  }
  for (int i=t; i<144*256*16; i+=stride){
    int s=i>>12, o=(i>>4)&255, kk=i&15;
    int kh = (s >= 72) ? 1 : 0;
    int r  = s - kh*72;
    int tap = r>>3, u = r&7;
    int ck = kh*128 + u*16 + kk;
    w2p[i] = f2bf(W2[o*2304 + ck*9 + tap]);
  }
  for (int i=t; i<256*64; i+=stride){ int c=i>>6, h=i&63; fc1t[i]=fc1w[h*256+c]; }
  for (int i=t; i<64*256; i+=stride){ int k=i>>8, c=i&255; fc2t[i]=fc2w[c*64+k]; }
}

__global__ __launch_bounds__(NTHREADS, 4) void lrb_main(
    const float* __restrict__ xg, const float* __restrict__ maskg,
    const float* __restrict__ g1, const float* __restrict__ b1,
    const float* __restrict__ g2, const float* __restrict__ b2,
    const unsigned short* __restrict__ w1p, const unsigned short* __restrict__ w2p,
    const float* __restrict__ fc1t, const float* __restrict__ fc1b,
    const float* __restrict__ fc2t, const float* __restrict__ fc2b,
    float* __restrict__ outg, float* __restrict__ gateg)
{
  extern __shared__ char smem[];
  float* OUTF = (float*)smem;                  // [NB][256][25] f32 reuses Y
  float* GB   = (float*)(smem + GB_OFF);
  float* MS   = (float*)(smem + MASK_OFF);
  float* POOL = (float*)(smem + POOL_OFF);
  float* HS   = (float*)(smem + H_OFF);
  float* GT   = (float*)(smem + GATE_OFF);
  float* INVD = (float*)(smem + INVD_OFF);

  const int tid  = threadIdx.x;
  const int lane = tid & 63;
  const int wid  = tid >> 6;     // 0..7
  const int mp   = wid >> 1;     // M-pair for conv2 (groups 2mp, 2mp+1)
  const int kh   = wid & 1;      // K-half for conv2; also kept sample
  const int p    = lane & 31;    // pixel slot (MFMA col / A row)
  const int half = lane >> 5;    // k-half within 16
  const int hx   = half << 4;    // byte offset of k-half within 32B k-slice
  const bool pv  = (p < 25);
  const int b0   = blockIdx.x * NB;

  // ---------------- phase 1: zero rows 25..48, stage params + mask ----------
  {
    int4 z4; z4.x=z4.y=z4.z=z4.w=0;
    for (int i = tid; i < NB*24*35; i += NTHREADS){
      int nbb = i / 840;
      int rem = i - nbb*840;
      int rr  = 25 + rem/35, cc = rem - (rem/35)*35;
      *(int4*)(smem + nbb*YSB + rr*CPB + cc*16) = z4;
    }
    if (tid < 256){
      GB[tid]=g1[tid]; GB[256+tid]=b1[tid]; GB[512+tid]=g2[tid]; GB[768+tid]=b2[tid];
    }
    if (tid >= 256 && tid < 256 + NB*32){
      int t2 = tid - 256;
      int nbb = t2>>5, pp = t2&31;
      MS[t2] = (pp < 25) ? maskg[(size_t)(b0+nbb)*25 + pp] : 0.f;
    }
  }

  // ---------------- geometry ----------------
  const int pr = p/5, ps = p - 5*(p/5);
  const int pbase = pv ? (7*pr + ps) : 0;
  const int bcol  = hx + kh*256;                 // byte column within row, conv2 B
  const char* w1c = (const char*)w1p;
  const char* w2c = (const char*)w2p;
  const int aoff1 = (wid*32 + p)*32 + hx;        // conv1 A byte off in panel
  // conv2 A: linear stream base for this wave's (kh, mp, p, half)
  const char* w2k = w2c + kh*589824 + mp*2048 + p*32 + hx;
  const char* Yb1[2] = { smem + p*CPB + hx, smem + YSB + p*CPB + hx };

  // conv1 A prologue (global; independent of LDS)
  v8s A1[3], B1[3][2];
  #pragma unroll
  for (int s0=0; s0<3; ++s0) A1[s0] = *(const v8s*)(w1c + s0*8192 + aoff1);

  // ---------------- phase 2: stage x -> Y rows 0..24 as bf16 [p][c] --------
  for (int i = tid; i < NB*25*32; i += NTHREADS){
    int nbb = i / 800;
    int rem = i - nbb*800;
    int pp  = rem >> 5;        // 0..24
    int c8  = rem & 31;        // channel octet
    const float* src = xg + ((size_t)(b0+nbb)*256 + c8*8)*25 + pp;
    v8s pk;
    #pragma unroll
    for (int k=0;k<8;++k) pk[k] = (short)f2bf(src[k*25]);
    *(v8s*)(smem + nbb*YSB + pp*CPB + c8*16) = pk;
  }
  __syncthreads();

  if (tid < NB){
    float s=0.f;
    #pragma unroll
    for (int pp=0;pp<25;++pp) s += MS[tid*32+pp];
    INVD[tid] = __builtin_amdgcn_rcpf(fmaxf(s, 1e-8f));
  }

  // ---------------- conv1 (1x1): 16 K-steps, wave = Mgroup wid -------------
  v16f acc1_0, acc1_1;
  #pragma unroll
  for (int j=0;j<16;++j){ acc1_0[j]=0.f; acc1_1[j]=0.f; }
  #pragma unroll
  for (int s0=0; s0<3; ++s0){
    B1[s0][0] = *(const v8s*)(Yb1[0] + s0*32);
    B1[s0][1] = *(const v8s*)(Yb1[1] + s0*32);
  }
  #pragma unroll
  for (int s=0; s<16; ++s){
    __builtin_amdgcn_s_setprio(1);
    acc1_0 = __builtin_amdgcn_mfma_f32_32x32x16_bf16(A1[s%3], B1[s%3][0], acc1_0, 0,0,0);
    acc1_1 = __builtin_amdgcn_mfma_f32_32x32x16_bf16(A1[s%3], B1[s%3][1], acc1_1, 0,0,0);
    __builtin_amdgcn_s_setprio(0);
    if (s+3 < 16){
      A1[s%3] = *(const v8s*)(w1c + (s+3)*8192 + aoff1);
      B1[s%3][0] = *(const v8s*)(Yb1[0] + (s+3)*32);
      B1[s%3][1] = *(const v8s*)(Yb1[1] + (s+3)*32);
    }
  }

  // ---------------- GN1 (wave's 32 ch = one group) + GELU -> grid ----------
  {
    float s0a=0.f,q0a=0.f,s1a=0.f,q1a=0.f;
    #pragma unroll
    for (int j=0;j<16;++j){
      float v0 = acc1_0[j], v1 = acc1_1[j];
      s0a+=v0; q0a+=v0*v0; s1a+=v1; q1a+=v1*v1;
    }
    #pragma unroll
    for (int off=1; off<64; off<<=1){
      s0a += __shfl_xor(s0a, off, 64); q0a += __shfl_xor(q0a, off, 64);
      s1a += __shfl_xor(s1a, off, 64); q1a += __shfl_xor(q1a, off, 64);
    }
    __syncthreads();   // all conv1 LDS reads complete before grid overwrite

    const int grow = pbase + 8;
    float mu0 = s0a*(1.f/800.f), mu1 = s1a*(1.f/800.f);
    float rstd0 = rsqrtf(q0a*(1.f/800.f) - mu0*mu0 + 1e-5f);
    float rstd1 = rsqrtf(q1a*(1.f/800.f) - mu1*mu1 + 1e-5f);
    if (pv){
      #pragma unroll
      for (int nt=0; nt<2; ++nt){
        float mu = nt ? mu1 : mu0, rstd = nt ? rstd1 : rstd0;
        char* dst = smem + nt*YSB + grow*CPB + wid*64 + half*8;
        #pragma unroll
        for (int q=0;q<4;++q){
          v4s pk;
          #pragma unroll
          for (int i2=0;i2<4;++i2){
            int ch = wid*32 + q*8 + half*4 + i2;
            float v = nt ? acc1_1[4*q+i2] : acc1_0[4*q+i2];
            float f = (v-mu)*rstd*GB[ch]+GB[256+ch];
            pk[i2] = (short)f2bf(gelu_f(f));
          }
          *(v4s*)(dst + q*16) = pk;
        }
      }
    }
  }
  // re-zero border rows dirtied by staging (rows 0..7,13,14,20,21)
  {
    int4 z4; z4.x=z4.y=z4.z=z4.w=0;
    for (int i = tid; i < NB*12*35; i += NTHREADS){
      int nbb = i / 420;
      int rem = i - nbb*420;
      int rr  = rem/35, cc = rem - (rem/35)*35;
      int row = rr < 8 ? rr : (rr < 10 ? rr + 5 : rr + 10);
      *(int4*)(smem + nbb*YSB + row*CPB + cc*16) = z4;
    }
  }

  // conv2 A prologue (global, linear stream) before the barrier
  v8s A2[3][2], B2[3][2];
  #pragma unroll
  for (int s0=0; s0<3; ++s0){
    A2[s0][0] = *(const v8s*)(w2k + s0*8192);
    A2[s0][1] = *(const v8s*)(w2k + s0*8192 + 1024);
  }
  __syncthreads();

  // ---------------- conv2: K-split, 72 steps/wave = 3 triples of 24 --------
  v16f acc2_00, acc2_01, acc2_10, acc2_11;   // [mg2][sample]
  #pragma unroll
  for (int j=0;j<16;++j){ acc2_00[j]=0.f; acc2_01[j]=0.f; acc2_10[j]=0.f; acc2_11[j]=0.f; }

  {
    int bq = pv ? pbase*CPB : 41*CPB;
    const int bd = pv ? 7*CPB : 0;
    int tb = 0;

    #pragma unroll
    for (int s0=0; s0<3; ++s0){
      B2[s0][0] = *(const v8s*)(smem + bq + bcol + s0*32);
      B2[s0][1] = *(const v8s*)(smem + YSB + bq + bcol + s0*32);
    }

#define C2_STEP(S, PF) do { \
    __builtin_amdgcn_s_setprio(1); \
    acc2_00 = __builtin_amdgcn_mfma_f32_32x32x16_bf16(A2[(S)%3][0], B2[(S)%3][0], acc2_00, 0,0,0); \
    acc2_01 = __builtin_amdgcn_mfma_f32_32x32x16_bf16(A2[(S)%3][0], B2[(S)%3][1], acc2_01, 0,0,0); \
    acc2_10 = __builtin_amdgcn_mfma_f32_32x32x16_bf16(A2[(S)%3][1], B2[(S)%3][0], acc2_10, 0,0,0); \
    acc2_11 = __builtin_amdgcn_mfma_f32_32x32x16_bf16(A2[(S)%3][1], B2[(S)%3][1], acc2_11, 0,0,0); \
    __builtin_amdgcn_s_setprio(0); \
    if (PF) { \
      const char* ap_ = w2k + tb + ((S)+3)*8192; \
      A2[(S)%3][0] = *(const v8s*)(ap_); \
      A2[(S)%3][1] = *(const v8s*)(ap_ + 1024); \
      const int ro_ = (((S)+3) < 24) ? (((S)+3)>>3)*CPB : 7*CPB; \
      const int co_ = (((S)+3)&7)*32; \
      B2[(S)%3][0] = *(const v8s*)(smem + bq + ro_ + bcol + co_); \
      B2[(S)%3][1] = *(const v8s*)(smem + YSB + bq + ro_ + bcol + co_); \
    } \
  } while(0)

    #pragma unroll 1
    for (int tr=0; tr<2; ++tr){
      #pragma unroll
      for (int s=0; s<24; ++s) C2_STEP(s, 1);
      tb += 196608;          // 24 panels * 8192
      bq += bd;              // +7 rows (OFF7 triple stride), 0 for invalid
    }
    #pragma unroll
    for (int s=0; s<21; ++s) C2_STEP(s, 1);
    #pragma unroll
    for (int s=21; s<24; ++s) C2_STEP(s, 0);
#undef C2_STEP
  }
  __syncthreads();   // conv2 LDS reads done; Y becomes exchange window

  // ---------------- cross-wave K-reduction via LDS overlay (2 rounds) ------
  {
    char* EXw = smem + (kh^1)*16384 + mp*4096 + (lane<<4);
    const char* EXr = smem + kh*16384 + mp*4096 + (lane<<4);
    if (kh==0) v16store(EXw, acc2_01); else v16store(EXw, acc2_00);
    __syncthreads();
    if (kh==0) v16addload(EXr, acc2_00); else v16addload(EXr, acc2_01);
    __syncthreads();
    if (kh==0) v16store(EXw, acc2_11); else v16store(EXw, acc2_10);
    __syncthreads();
    if (kh==0) v16addload(EXr, acc2_10); else v16addload(EXr, acc2_11);
  }
  // kept sample = kh; F0 = group 2mp, F1 = group 2mp+1
  v16f F0 = (kh==0) ? acc2_00 : acc2_01;
  v16f F1 = (kh==0) ? acc2_10 : acc2_11;

  // ---------------- GN2 + GELU + residual -> OUTF ----------
  {
    float s0a=0.f,q0a=0.f,s1a=0.f,q1a=0.f;
    #pragma unroll
    for (int j=0;j<16;++j){
      float v0=F0[j], v1=F1[j];
      s0a+=v0; q0a+=v0*v0; s1a+=v1; q1a+=v1*v1;
    }
    #pragma unroll
    for (int off=1; off<64; off<<=1){
      s0a += __shfl_xor(s0a, off, 64); q0a += __shfl_xor(q0a, off, 64);
      s1a += __shfl_xor(s1a, off, 64); q1a += __shfl_xor(q1a, off, 64);
    }
    __syncthreads();   // exchange reads complete; OUTF region free

    float mu0 = s0a*(1.f/800.f), mu1 = s1a*(1.f/800.f);
    float rstd0 = rsqrtf(q0a*(1.f/800.f) - mu0*mu0 + 1e-5f);
    float rstd1 = rsqrtf(q1a*(1.f/800.f) - mu1*mu1 + 1e-5f);
    const float* xr = xg + ((size_t)(b0+kh)*256 + mp*64)*25 + p;
    if (pv){
      #pragma unroll
      for (int j=0;j<16;++j){
        int crow = (j&3) + 8*(j>>2) + 4*half;
        {
          int ch = mp*64 + crow;
          float f = (F0[j]-mu0)*rstd0*GB[512+ch]+GB[768+ch];
          f = gelu_f(f) + xr[crow*25];
          OUTF[kh*6400 + ch*25 + p] = f;
        }
        {
          int ch = mp*64 + 32 + crow;
          float f = (F1[j]-mu1)*rstd1*GB[512+ch]+GB[768+ch];
          f = gelu_f(f) + xr[(32+crow)*25];
          OUTF[kh*6400 + ch*25 + p] = f;
        }
      }
    }
  }
  __syncthreads();

  // ---------------- masked pooling via OUTF re-read (conflict-free) --------
  {
    int nbb = tid >> 8, ch = tid & 255;
    const float* of = OUTF + nbb*6400 + ch*25;
    const float* ms = MS + nbb*32;
    float dot = 0.f;
    #pragma unroll
    for (int pp=0; pp<25; ++pp) dot = fmaf(of[pp], ms[pp], dot);
    POOL[nbb*256 + ch] = dot;
  }
  __syncthreads();

  // ---------------- SE FC1: 4-way split dot + shuffle combine --------------
  {
    int nbb  = tid >> 8;          // 0..1
    int hid  = (tid >> 2) & 63;
    int part = tid & 3;
    const float* pl = POOL + nbb*256 + part*64;
    const float* wp = fc1t + part*64*64 + hid;
    float dot = 0.f;
    #pragma unroll 8
    for (int c=0;c<64;++c) dot += wp[c*64]*pl[c];
    dot += __shfl_xor(dot, 1, 64);
    dot += __shfl_xor(dot, 2, 64);
    if (part == 0)
      HS[nbb*64+hid] = gelu_f(fmaf(INVD[nbb], dot, fc1b[hid]));
  }
  __syncthreads();
  // ---------------- SE FC2 -> sigmoid gate (LDS + global) -----------------
  {
    int ch = tid & 255, nbb = tid >> 8;
    const float* hp = HS + nbb*64;
    float dot = 0.f;
    #pragma unroll 8
    for (int k=0;k<64;++k) dot += fc2t[k*256+ch]*hp[k];
    dot += fc2b[ch];
    float gv = __builtin_amdgcn_rcpf(1.0f + __builtin_amdgcn_exp2f(-dot*1.4426950408889634f));
    GT[nbb*256+ch] = gv;
    gateg[(size_t)(b0+nbb)*256+ch] = gv;
  }
  __syncthreads();

  // ---------------- final coalesced store: out = OUTF * gate * mask -------
  for (int i = tid; i < NB*1600; i += NTHREADS){
    int nbb = i / 1600;
    int r4  = i - nbb*1600;
    int e0  = r4*4;
    v4f o4 = *(const v4f*)(OUTF + nbb*6400 + e0);
    #pragma unroll
    for (int k=0;k<4;++k){
      int e = e0+k;
      int ch = e/25;
      int pp = e - ch*25;
      o4[k] = o4[k] * GT[nbb*256+ch] * MS[nbb*32+pp];
    }
    *(v4f*)(outg + (size_t)(b0+nbb)*6400 + e0) = o4;
  }
}

extern "C" void kernel_launch(void* const* d_in, const int* in_sizes, int n_in,
                              void* d_out, int out_size, void* d_ws, size_t ws_size,
                              hipStream_t stream)
{
  const float* xg   = (const float*)d_in[0];
  const float* pm   = (const float*)d_in[1];
  const float* W1   = (const float*)d_in[2];
  const float* g1   = (const float*)d_in[3];
  const float* b1   = (const float*)d_in[4];
  const float* W2   = (const float*)d_in[5];
  const float* g2   = (const float*)d_in[6];
  const float* b2   = (const float*)d_in[7];
  const float* fc1w = (const float*)d_in[8];
  const float* fc1b = (const float*)d_in[9];
  const float* fc2w = (const float*)d_in[10];
  const float* fc2b = (const float*)d_in[11];

  float* outg  = (float*)d_out;
  float* gateg = outg + (size_t)8192*256*25;

  unsigned short* w1p = (unsigned short*)d_ws;        // 16*256*16 bf16
  unsigned short* w2p = w1p + 16*256*16;              // 144*256*16 bf16 (kh-major linear)
  float* fc1t = (float*)(w2p + 144*256*16);           // 256*64 f32 (transposed)
  float* fc2t = fc1t + 256*64;                        // 64*256 f32 (transposed)

  prep_kernel<<<dim3(512), dim3(256), 0, stream>>>(W1, W2, fc1w, fc2w, w1p, w2p, fc1t, fc2t);

  hipFuncSetAttribute(reinterpret_cast<const void*>(lrb_main),
                      hipFuncAttributeMaxDynamicSharedMemorySize, (int)SMEM_BYTES);
  lrb_main<<<dim3(4096), dim3(NTHREADS), SMEM_BYTES, stream>>>(
      xg, pm, g1, b1, g2, b2, w1p, w2p, fc1t, fc1b, fc2t, fc2b, outg, gateg);
}